// Round 16
// baseline (10725.296 us; speedup 1.0000x reference)
//
#include <hip/hip_runtime.h>
#include <stdint.h>

#define T_STEPS 101
#define ROWS 1600
#define NTHR 1024
#define NBLK 256            /* 4 batches per block, 1024 batches total */
#define NP1 20              /* L1: 40 nz = 20 pairs */
#define NP23 25             /* L2/3: 50 nz = 25 pairs */

/* ws byte offsets: row-contiguous 16B records per layer */
#define REC1_OFF 0                         /* 1600*20*16 = 512000 */
#define REC2_OFF 512000                    /* 1600*25*16 = 640000 */
#define REC3_OFF 1152000                   /* 640000 */
#define BB_OFF   1792000                   /* float2 {beta,bias} [3][1600] */
#define SA_OFF   (BB_OFF + 3 * ROWS * 8)   /* float sigmoid(tau_m) [3][200] */

typedef float v2f __attribute__((ext_vector_type(2)));
__device__ __forceinline__ v2f fma2(v2f a, v2f b, v2f c) {
  return __builtin_elementwise_fma(a, b, c);   // v_pk_fma_f32: per-comp IEEE fma
}

__device__ __forceinline__ float sigmoidf(float v) { return 1.0f / (1.0f + expf(-v)); }

// ---------------------------------------------------------------------------
// Prep: row-contiguous 16B records {w0, w1, colpair, pad} -- one b128 load
// with immediate offset per pair in the main kernel. Ascending col order
// (round-1's verified op order); padding w=0/c=0 exact. Offset scales:
// L1 col*16 (float4 k1 table), L2/3 col*4 (u8-quad tables).
// ---------------------------------------------------------------------------
__global__ void prep_kernel(const float* __restrict__ W1, const float* __restrict__ W2,
                            const float* __restrict__ W3,
                            const float* __restrict__ b1, const float* __restrict__ tn1,
                            const float* __restrict__ tm1,
                            const float* __restrict__ b2, const float* __restrict__ tn2,
                            const float* __restrict__ tm2,
                            const float* __restrict__ b3, const float* __restrict__ tn3,
                            const float* __restrict__ tm3,
                            uint8_t* __restrict__ ws) {
  int gid = blockIdx.x * blockDim.x + threadIdx.x;
  if (gid >= 3 * ROWS) return;
  int l = gid / ROWS, r = gid - l * ROWS;
  const float *W, *bb, *tn, *tm; int in_f, knz, np, roff, scale;
  if (l == 0)      { W = W1; bb = b1; tn = tn1; tm = tm1; in_f = 320; knz = 40; np = NP1;  roff = REC1_OFF; scale = 16; }
  else if (l == 1) { W = W2; bb = b2; tn = tn2; tm = tm2; in_f = 400; knz = 50; np = NP23; roff = REC2_OFF; scale = 4; }
  else             { W = W3; bb = b3; tn = tn3; tm = tm3; in_f = 400; knz = 50; np = NP23; roff = REC3_OFF; scale = 4; }
  float4* rec = (float4*)(ws + roff);
  float wl[52]; uint32_t cl[52];
  int cnt = 0;
  for (int col = 0; col < in_f; ++col) {
    float w = W[(size_t)r * in_f + col];
    if (w != 0.0f && cnt < knz) { wl[cnt] = w; cl[cnt] = (uint32_t)(col * scale); ++cnt; }
  }
  for (; cnt < 2 * np; ++cnt) { wl[cnt] = 0.0f; cl[cnt] = 0u; }
  for (int p = 0; p < np; ++p) {
    float4 rv;
    rv.x = wl[2 * p]; rv.y = wl[2 * p + 1];
    rv.z = __uint_as_float(cl[2 * p] | (cl[2 * p + 1] << 16));
    rv.w = 0.0f;
    rec[(size_t)r * np + p] = rv;
  }
  ((float2*)(ws + BB_OFF))[l * ROWS + r] = make_float2(sigmoidf(tn[r]), bb[r]);
  if (r < 200) ((float*)(ws + SA_OFF))[l * 200 + r] = sigmoidf(tm[r]);
}

// ---------------------------------------------------------------------------
// One row-slot, 4 batch lanes. Per pair: ONE b128 record load (imm offset)
// + 2 LDS reads + 4 v_pk_fma_f32. Per-batch fma chains are bitwise
// identical to the verified r15 kernel (pk_fma = 2x IEEE fma). Leader
// writes spike word into consumer tables per template flags.
// ---------------------------------------------------------------------------
template<int NP, bool F32, bool WA, bool WB, bool WK1>
__device__ __forceinline__ void slot_compute(
    int tid, int r, const float4* __restrict__ rec,
    const uint8_t* __restrict__ ktab,
    const float2* __restrict__ bbL, const float* __restrict__ saL,
    v2f (&dreg)[2], uint8_t (*s_l)[4], float (*mem_l)[4],
    uint8_t (*spA)[4], uint8_t (*spB)[4], float4* k1n)
{
  const float2 bb = bbL[r];
  const float bt = bb.x;
  v2f a01 = {bb.y, bb.y}, a23 = {bb.y, bb.y};
  const float4* rp = rec + (size_t)r * NP;
#pragma unroll 5
  for (int p = 0; p < NP; ++p) {
    const float4 rv = rp[p];
    const v2f wx = {rv.x, rv.x}, wy = {rv.y, rv.y};
    const uint32_t c = __float_as_uint(rv.z);
    if constexpr (F32) {
      { const float4 kv = *reinterpret_cast<const float4*>(ktab + (c & 0xffffu));
        a01 = fma2(wx, (v2f){kv.x, kv.y}, a01);
        a23 = fma2(wx, (v2f){kv.z, kv.w}, a23); }
      { const float4 kv = *reinterpret_cast<const float4*>(ktab + (c >> 16));
        a01 = fma2(wy, (v2f){kv.x, kv.y}, a01);
        a23 = fma2(wy, (v2f){kv.z, kv.w}, a23); }
    } else {
      { const uint32_t q = *reinterpret_cast<const uint32_t*>(ktab + (c & 0xffffu));
        a01 = fma2(wx, (v2f){(float)(q & 0xffu), (float)((q >> 8) & 0xffu)}, a01);
        a23 = fma2(wx, (v2f){(float)((q >> 16) & 0xffu), (float)(q >> 24)}, a23); }
      { const uint32_t q = *reinterpret_cast<const uint32_t*>(ktab + (c >> 16));
        a01 = fma2(wy, (v2f){(float)(q & 0xffu), (float)((q >> 8) & 0xffu)}, a01);
        a23 = fma2(wy, (v2f){(float)((q >> 16) & 0xffu), (float)(q >> 24)}, a23); }
    }
  }
  const v2f bt2 = {bt, bt}, ob2 = {1.0f - bt, 1.0f - bt};
  const v2f d01v = fma2(bt2, dreg[0], ob2 * a01);
  const v2f d23v = fma2(bt2, dreg[1], ob2 * a23);
  dreg[0] = d01v; dreg[1] = d23v;
  float d0 = d01v.x, d1 = d01v.y, d2 = d23v.x, d3 = d23v.y;
  d0 += __shfl_xor(d0, 1); d0 += __shfl_xor(d0, 2); d0 += __shfl_xor(d0, 4);
  d1 += __shfl_xor(d1, 1); d1 += __shfl_xor(d1, 2); d1 += __shfl_xor(d1, 4);
  d2 += __shfl_xor(d2, 1); d2 += __shfl_xor(d2, 2); d2 += __shfl_xor(d2, 4);
  d3 += __shfl_xor(d3, 1); d3 += __shfl_xor(d3, 2); d3 += __shfl_xor(d3, 4);
  if ((tid & 7) == 0) {
    const int n = r >> 3;
    const float al = saL[n], oa = 1.0f - al;
    float4 mv = *reinterpret_cast<float4*>(&mem_l[n][0]);
    const uint32_t so = *reinterpret_cast<uint32_t*>(&s_l[n][0]);
    const float m0 = fmaf(mv.x - (float)(so & 0xffu),         al, oa * d0);
    const float m1 = fmaf(mv.y - (float)((so >> 8) & 0xffu),  al, oa * d1);
    const float m2 = fmaf(mv.z - (float)((so >> 16) & 0xffu), al, oa * d2);
    const float m3 = fmaf(mv.w - (float)(so >> 24),           al, oa * d3);
    *reinterpret_cast<float4*>(&mem_l[n][0]) = make_float4(m0, m1, m2, m3);
    const uint32_t sn = (m0 > 1.0f ? 1u : 0u) | (m1 > 1.0f ? 0x100u : 0u)
                      | (m2 > 1.0f ? 0x10000u : 0u) | (m3 > 1.0f ? 0x1000000u : 0u);
    *reinterpret_cast<uint32_t*>(&s_l[n][0]) = sn;
    if constexpr (WA) *reinterpret_cast<uint32_t*>(&spA[n][0]) = sn;
    if constexpr (WB) *reinterpret_cast<uint32_t*>(&spB[n][0]) = sn;
    if constexpr (WK1)
      k1n[120 + n] = make_float4(m0 > 1.0f ? 1.0f : 0.0f, m1 > 1.0f ? 1.0f : 0.0f,
                                 m2 > 1.0f ? 1.0f : 0.0f, m3 > 1.0f ? 1.0f : 0.0f);
  }
}

// ---------------------------------------------------------------------------
// Main kernel: 256 blocks x 1024 threads, 4 batches/block, layer-skewed
// pipeline (verified r15 schedule): super-step u runs {L1(u), L2(u-1),
// L3(u-2), readout(u-3), x-stage(u+1)} in one barrier phase; 75 wave-slots
// grid-strided over 16 waves.
// ---------------------------------------------------------------------------
__global__ void __launch_bounds__(NTHR)
snn_main(const float* __restrict__ x,
         const float* __restrict__ W4, const float* __restrict__ b4,
         const float* __restrict__ tm4,
         const float4* __restrict__ rec1, const float4* __restrict__ rec2,
         const float4* __restrict__ rec3,
         const float2* __restrict__ bbG, const float* __restrict__ saG,
         float* __restrict__ out)
{
  __shared__ __align__(16) float4   k1f[2][320];       // parity: x(t) | s1(t-1)
  __shared__ __align__(4)  uint8_t  k2tab[2][400][4];  // parity: s1(t) | s2(t-1)
  __shared__ __align__(4)  uint8_t  k3tab[2][400][4];  // parity: s2(t) | s3(t-1)
  __shared__ __align__(4)  uint8_t  s_lds[3][200][4];
  __shared__ __align__(16) float    mem_lds[3][200][4];
  __shared__ float  w4_lds[12][201];
  __shared__ float2 bbL[3 * ROWS];
  __shared__ float  saL[3 * 200];
  __shared__ float  smx[12][4];

  const int tid = threadIdx.x;
  const int wv  = tid >> 6;
  const int bg  = blockIdx.x;          // batches bg*4 .. bg*4+3

  for (int idx = tid; idx < 600; idx += NTHR) {
    reinterpret_cast<uint32_t*>(&s_lds[0][0][0])[idx] = 0u;
    reinterpret_cast<float4*>(&mem_lds[0][0][0])[idx] = make_float4(0.f, 0.f, 0.f, 0.f);
  }
  for (int idx = tid; idx < 800; idx += NTHR) {        // zero both parities
    reinterpret_cast<uint32_t*>(&k2tab[0][0][0])[idx] = 0u;
    reinterpret_cast<uint32_t*>(&k3tab[0][0][0])[idx] = 0u;
  }
  for (int idx = tid; idx < 200; idx += NTHR)          // s1(-1) = 0
    k1f[0][120 + idx] = make_float4(0.f, 0.f, 0.f, 0.f);
  for (int idx = tid; idx < 12 * 200; idx += NTHR)
    w4_lds[idx / 200][idx % 200] = W4[idx];
  for (int idx = tid; idx < 3 * ROWS; idx += NTHR) bbL[idx] = bbG[idx];
  for (int idx = tid; idx < 3 * 200; idx += NTHR) saL[idx] = saG[idx];
  if (tid < 480) {                                     // x(0) -> k1f[0]
    const int bat = tid / 120, cf = tid - bat * 120;
    const int c = cf / 40, f = cf - c * 40;
    reinterpret_cast<float*>(&k1f[0][cf])[bat] =
        x[(((size_t)(bg * 4 + bat) * 3 + c) * T_STEPS) * 40 + f];
  }

  v2f d[5][2];
#pragma unroll
  for (int k = 0; k < 5; ++k) { d[k][0] = (v2f){0.f, 0.f}; d[k][1] = (v2f){0.f, 0.f}; }

  // readout constants (waves 11-13: 192 threads)
  float m4_reg = 0.0f, m4_acc = 0.0f, a4 = 0.0f, b4r = 0.0f;
  if (tid >= 704 && tid < 896) {
    const int o = (tid - 704) >> 4;
    a4 = sigmoidf(tm4[o]); b4r = b4[o];
  }
  __syncthreads();

  const int lane = tid & 63;

  for (int u = 0; u <= T_STEPS + 2; ++u) {
    const int cur = u & 1, oth = cur ^ 1;
    const uint8_t* k1b = reinterpret_cast<const uint8_t*>(&k1f[cur][0]);
    const uint8_t* k2b = reinterpret_cast<const uint8_t*>(&k2tab[oth][0][0]);
    const uint8_t* k3b = reinterpret_cast<const uint8_t*>(&k3tab[cur][0][0]);
    const bool runL1 = (u <= T_STEPS - 1);
    const bool runL2 = (u >= 1 && u <= T_STEPS);
    const bool runL3 = (u >= 2 && u <= T_STEPS + 1);
#pragma unroll
    for (int k = 0; k < 5; ++k) {
      const int id = wv + 16 * k;
      if (id >= 75) break;                   // wave-uniform
      const int layer = id / 25;
      const int r = (id - layer * 25) * 64 + lane;
      if (layer == 0) {
        if (runL1)
          slot_compute<NP1, true, true, false, true>(
              tid, r, rec1, k1b, bbL, saL, d[k], s_lds[0], mem_lds[0],
              k2tab[cur], k2tab[cur], k1f[oth]);
      } else if (layer == 1) {
        if (runL2)
          slot_compute<NP23, false, true, true, false>(
              tid, r, rec2, k2b, bbL + ROWS, saL + 200,
              d[k], s_lds[1], mem_lds[1], k3tab[oth], k2tab[cur] + 200, nullptr);
      } else {
        if (runL3)
          slot_compute<NP23, false, false, true, false>(
              tid, r, rec3, k3b, bbL + 2 * ROWS, saL + 400,
              d[k], s_lds[2], mem_lds[2], nullptr, k3tab[oth] + 200, nullptr);
      }
    }
    // ---- light-wave duties ---------------------------------------------
    if (wv >= 14) {
      // x-stage for t = u+1
      if (u + 1 <= T_STEPS - 1) {
        const int rid = tid - 896;
        for (int e = rid; e < 480; e += 128) {
          const int bat = e / 120, cf = e - bat * 120;
          const int c = cf / 40, f = cf - c * 40;
          reinterpret_cast<float*>(&k1f[oth][cf])[bat] =
              x[(((size_t)(bg * 4 + bat) * 3 + c) * T_STEPS + (u + 1)) * 40 + f];
        }
      }
    } else if (wv >= 11) {
      // readout for t_r = u-3 (s3(t_r) lives in k3tab[cur][200..])
      if (u >= 3) {
        const int rid = tid - 704;
        const int sub = rid & 3;
        float part = 0.0f;
#pragma unroll 10
        for (int m = 0; m < 50; ++m) {
          const int n = 4 * m + sub;
          part = fmaf(w4_lds[rid >> 4][n], (float)k3tab[cur][200 + n][(rid >> 2) & 3], part);
        }
        part += __shfl_xor(part, 1);
        part += __shfl_xor(part, 2);
        const float dot = b4r + part;
        m4_reg = a4 * m4_reg + (1.0f - a4) * dot;
        m4_acc += m4_reg;
      }
    }
    __syncthreads();
  }

  // ---- epilogue: log_softmax(acc / T) ----------------------------------
  if (tid >= 704 && tid < 896 && ((tid - 704) & 3) == 0) {
    const int rid = tid - 704;
    smx[rid >> 4][(rid >> 2) & 3] = m4_acc * (1.0f / (float)T_STEPS);
  }
  __syncthreads();
  if (tid < 4) {
    const int bat = tid;
    float v[12], mx = -1e30f;
#pragma unroll
    for (int o = 0; o < 12; ++o) { v[o] = smx[o][bat]; mx = fmaxf(mx, v[o]); }
    float s = 0.0f;
#pragma unroll
    for (int o = 0; o < 12; ++o) s += expf(v[o] - mx);
    const float ls = logf(s);
#pragma unroll
    for (int o = 0; o < 12; ++o)
      out[((size_t)(bg * 4 + bat)) * 12 + o] = v[o] - mx - ls;
  }
}

// ---------------------------------------------------------------------------
extern "C" void kernel_launch(void* const* d_in, const int* in_sizes, int n_in,
                              void* d_out, int out_size, void* d_ws, size_t ws_size,
                              hipStream_t stream) {
  (void)in_sizes; (void)n_in; (void)out_size; (void)ws_size;
  const float* x   = (const float*)d_in[0];
  const float* W1  = (const float*)d_in[1];
  const float* b1  = (const float*)d_in[2];
  const float* tm1 = (const float*)d_in[3];
  const float* tn1 = (const float*)d_in[4];
  const float* W2  = (const float*)d_in[5];
  const float* b2  = (const float*)d_in[6];
  const float* tm2 = (const float*)d_in[7];
  const float* tn2 = (const float*)d_in[8];
  const float* W3  = (const float*)d_in[9];
  const float* b3  = (const float*)d_in[10];
  const float* tm3 = (const float*)d_in[11];
  const float* tn3 = (const float*)d_in[12];
  const float* W4  = (const float*)d_in[13];
  const float* b4  = (const float*)d_in[14];
  const float* tm4 = (const float*)d_in[15];

  uint8_t* ws = (uint8_t*)d_ws;
  const float4* rec1 = (const float4*)(ws + REC1_OFF);
  const float4* rec2 = (const float4*)(ws + REC2_OFF);
  const float4* rec3 = (const float4*)(ws + REC3_OFF);
  const float2* bbG  = (const float2*)(ws + BB_OFF);
  const float*  saG  = (const float*)(ws + SA_OFF);

  prep_kernel<<<dim3(19), dim3(256), 0, stream>>>(
      W1, W2, W3, b1, tn1, tm1, b2, tn2, tm2, b3, tn3, tm3, ws);
  snn_main<<<dim3(NBLK), dim3(NTHR), 0, stream>>>(
      x, W4, b4, tm4, rec1, rec2, rec3, bbG, saG, (float*)d_out);
}

// Round 17
// 2713.844 us; speedup vs baseline: 3.9521x; 3.9521x over previous
//
#include <hip/hip_runtime.h>
#include <stdint.h>

#define T_STEPS 101
#define ROWS 1600
#define NTHR 1024
#define NBLK 256            /* 4 batches per block, 1024 batches total */
#define NP1 20              /* L1: 40 nz = 20 pairs */
#define NP23 25             /* L2/3: 50 nz = 25 pairs */
#define PO2 (NP1 * ROWS)               /* 32000 pairs */
#define PO3 (PO2 + NP23 * ROWS)        /* 72000 */
#define NPTOT (PO3 + NP23 * ROWS)      /* 112000 pairs */

/* ws byte offsets */
#define ENT_OFF 0                          /* float4 SoA [p][1600]: 1792000 B */
#define BB_OFF  (NPTOT * 16)               /* float2 {beta,bias} [3][1600] */
#define SA_OFF  (BB_OFF + 3 * ROWS * 8)    /* float sigmoid(tau_m) [3][200] */

typedef float v2f __attribute__((ext_vector_type(2)));
__device__ __forceinline__ v2f fma2(v2f a, v2f b, v2f c) {
  return __builtin_elementwise_fma(a, b, c);   // v_pk_fma_f32: per-comp IEEE fma
}

__device__ __forceinline__ float sigmoidf(float v) { return 1.0f / (1.0f + expf(-v)); }

// ---------------------------------------------------------------------------
// Prep: fused pair records {w0, w1, colpair, pad} in SoA [pair][1600] layout
// (consecutive lanes -> consecutive r -> coalesced 1KB/wave loads; round 16's
// row-contiguous layout broke coalescing and regressed 4x). Ascending col
// order == round-1's verified op order; padding w=0/c=0 exact.
// Offset scales: L1 col*16 (float4 k1 table), L2/3 col*4 (u8-quad tables).
// ---------------------------------------------------------------------------
__global__ void prep_kernel(const float* __restrict__ W1, const float* __restrict__ W2,
                            const float* __restrict__ W3,
                            const float* __restrict__ b1, const float* __restrict__ tn1,
                            const float* __restrict__ tm1,
                            const float* __restrict__ b2, const float* __restrict__ tn2,
                            const float* __restrict__ tm2,
                            const float* __restrict__ b3, const float* __restrict__ tn3,
                            const float* __restrict__ tm3,
                            uint8_t* __restrict__ ws) {
  int gid = blockIdx.x * blockDim.x + threadIdx.x;
  if (gid >= 3 * ROWS) return;
  int l = gid / ROWS, r = gid - l * ROWS;
  const float *W, *bb, *tn, *tm; int in_f, knz, np, poff, scale;
  if (l == 0)      { W = W1; bb = b1; tn = tn1; tm = tm1; in_f = 320; knz = 40; np = NP1;  poff = 0;   scale = 16; }
  else if (l == 1) { W = W2; bb = b2; tn = tn2; tm = tm2; in_f = 400; knz = 50; np = NP23; poff = PO2; scale = 4; }
  else             { W = W3; bb = b3; tn = tn3; tm = tm3; in_f = 400; knz = 50; np = NP23; poff = PO3; scale = 4; }
  float4* ent = (float4*)(ws + ENT_OFF) + poff;
  float wl[52]; uint32_t cl[52];
  int cnt = 0;
  for (int col = 0; col < in_f; ++col) {
    float w = W[(size_t)r * in_f + col];
    if (w != 0.0f && cnt < knz) { wl[cnt] = w; cl[cnt] = (uint32_t)(col * scale); ++cnt; }
  }
  for (; cnt < 2 * np; ++cnt) { wl[cnt] = 0.0f; cl[cnt] = 0u; }
  for (int p = 0; p < np; ++p) {
    float4 rv;
    rv.x = wl[2 * p]; rv.y = wl[2 * p + 1];
    rv.z = __uint_as_float(cl[2 * p] | (cl[2 * p + 1] << 16));
    rv.w = 0.0f;
    ent[p * ROWS + r] = rv;
  }
  ((float2*)(ws + BB_OFF))[l * ROWS + r] = make_float2(sigmoidf(tn[r]), bb[r]);
  if (r < 200) ((float*)(ws + SA_OFF))[l * 200 + r] = sigmoidf(tm[r]);
}

// ---------------------------------------------------------------------------
// One row-slot, 4 batch lanes. Per pair: ONE coalesced b128 entry load +
// 2 LDS reads + 4 v_pk_fma_f32. pk_fma chains verified bitwise (r16,
// absmax 0.0). Leader writes spike word into consumer tables per flags.
// ---------------------------------------------------------------------------
template<int NP, bool F32, bool WA, bool WB, bool WK1>
__device__ __forceinline__ void slot_compute(
    int tid, int r, const float4* __restrict__ ent,
    const uint8_t* __restrict__ ktab,
    const float2* __restrict__ bbL, const float* __restrict__ saL,
    v2f (&dreg)[2], uint8_t (*s_l)[4], float (*mem_l)[4],
    uint8_t (*spA)[4], uint8_t (*spB)[4], float4* k1n)
{
  const float2 bb = bbL[r];
  const float bt = bb.x;
  v2f a01 = {bb.y, bb.y}, a23 = {bb.y, bb.y};
  const float4* ep = ent + r;
#pragma unroll 5
  for (int p = 0; p < NP; ++p) {
    const float4 rv = ep[(size_t)p * ROWS];
    const v2f wx = {rv.x, rv.x}, wy = {rv.y, rv.y};
    const uint32_t c = __float_as_uint(rv.z);
    if constexpr (F32) {
      { const float4 kv = *reinterpret_cast<const float4*>(ktab + (c & 0xffffu));
        a01 = fma2(wx, (v2f){kv.x, kv.y}, a01);
        a23 = fma2(wx, (v2f){kv.z, kv.w}, a23); }
      { const float4 kv = *reinterpret_cast<const float4*>(ktab + (c >> 16));
        a01 = fma2(wy, (v2f){kv.x, kv.y}, a01);
        a23 = fma2(wy, (v2f){kv.z, kv.w}, a23); }
    } else {
      { const uint32_t q = *reinterpret_cast<const uint32_t*>(ktab + (c & 0xffffu));
        a01 = fma2(wx, (v2f){(float)(q & 0xffu), (float)((q >> 8) & 0xffu)}, a01);
        a23 = fma2(wx, (v2f){(float)((q >> 16) & 0xffu), (float)(q >> 24)}, a23); }
      { const uint32_t q = *reinterpret_cast<const uint32_t*>(ktab + (c >> 16));
        a01 = fma2(wy, (v2f){(float)(q & 0xffu), (float)((q >> 8) & 0xffu)}, a01);
        a23 = fma2(wy, (v2f){(float)((q >> 16) & 0xffu), (float)(q >> 24)}, a23); }
    }
  }
  const v2f bt2 = {bt, bt}, ob2 = {1.0f - bt, 1.0f - bt};
  const v2f d01v = fma2(bt2, dreg[0], ob2 * a01);
  const v2f d23v = fma2(bt2, dreg[1], ob2 * a23);
  dreg[0] = d01v; dreg[1] = d23v;
  float d0 = d01v.x, d1 = d01v.y, d2 = d23v.x, d3 = d23v.y;
  d0 += __shfl_xor(d0, 1); d0 += __shfl_xor(d0, 2); d0 += __shfl_xor(d0, 4);
  d1 += __shfl_xor(d1, 1); d1 += __shfl_xor(d1, 2); d1 += __shfl_xor(d1, 4);
  d2 += __shfl_xor(d2, 1); d2 += __shfl_xor(d2, 2); d2 += __shfl_xor(d2, 4);
  d3 += __shfl_xor(d3, 1); d3 += __shfl_xor(d3, 2); d3 += __shfl_xor(d3, 4);
  if ((tid & 7) == 0) {
    const int n = r >> 3;
    const float al = saL[n], oa = 1.0f - al;
    float4 mv = *reinterpret_cast<float4*>(&mem_l[n][0]);
    const uint32_t so = *reinterpret_cast<uint32_t*>(&s_l[n][0]);
    const float m0 = fmaf(mv.x - (float)(so & 0xffu),         al, oa * d0);
    const float m1 = fmaf(mv.y - (float)((so >> 8) & 0xffu),  al, oa * d1);
    const float m2 = fmaf(mv.z - (float)((so >> 16) & 0xffu), al, oa * d2);
    const float m3 = fmaf(mv.w - (float)(so >> 24),           al, oa * d3);
    *reinterpret_cast<float4*>(&mem_l[n][0]) = make_float4(m0, m1, m2, m3);
    const uint32_t sn = (m0 > 1.0f ? 1u : 0u) | (m1 > 1.0f ? 0x100u : 0u)
                      | (m2 > 1.0f ? 0x10000u : 0u) | (m3 > 1.0f ? 0x1000000u : 0u);
    *reinterpret_cast<uint32_t*>(&s_l[n][0]) = sn;
    if constexpr (WA) *reinterpret_cast<uint32_t*>(&spA[n][0]) = sn;
    if constexpr (WB) *reinterpret_cast<uint32_t*>(&spB[n][0]) = sn;
    if constexpr (WK1)
      k1n[120 + n] = make_float4(m0 > 1.0f ? 1.0f : 0.0f, m1 > 1.0f ? 1.0f : 0.0f,
                                 m2 > 1.0f ? 1.0f : 0.0f, m3 > 1.0f ? 1.0f : 0.0f);
  }
}

// ---------------------------------------------------------------------------
// Main kernel: 256 blocks x 1024 threads, 4 batches/block, layer-skewed
// pipeline (verified r15 schedule): super-step u runs {L1(u), L2(u-1),
// L3(u-2), readout(u-3), x-stage(u+1)} in one barrier phase; 75 wave-slots
// grid-strided over 16 waves.
// ---------------------------------------------------------------------------
__global__ void __launch_bounds__(NTHR)
snn_main(const float* __restrict__ x,
         const float* __restrict__ W4, const float* __restrict__ b4,
         const float* __restrict__ tm4,
         const float4* __restrict__ ent1, const float4* __restrict__ ent2,
         const float4* __restrict__ ent3,
         const float2* __restrict__ bbG, const float* __restrict__ saG,
         float* __restrict__ out)
{
  __shared__ __align__(16) float4   k1f[2][320];       // parity: x(t) | s1(t-1)
  __shared__ __align__(4)  uint8_t  k2tab[2][400][4];  // parity: s1(t) | s2(t-1)
  __shared__ __align__(4)  uint8_t  k3tab[2][400][4];  // parity: s2(t) | s3(t-1)
  __shared__ __align__(4)  uint8_t  s_lds[3][200][4];
  __shared__ __align__(16) float    mem_lds[3][200][4];
  __shared__ float  w4_lds[12][201];
  __shared__ float2 bbL[3 * ROWS];
  __shared__ float  saL[3 * 200];
  __shared__ float  smx[12][4];

  const int tid = threadIdx.x;
  const int wv  = tid >> 6;
  const int bg  = blockIdx.x;          // batches bg*4 .. bg*4+3

  for (int idx = tid; idx < 600; idx += NTHR) {
    reinterpret_cast<uint32_t*>(&s_lds[0][0][0])[idx] = 0u;
    reinterpret_cast<float4*>(&mem_lds[0][0][0])[idx] = make_float4(0.f, 0.f, 0.f, 0.f);
  }
  for (int idx = tid; idx < 800; idx += NTHR) {        // zero both parities
    reinterpret_cast<uint32_t*>(&k2tab[0][0][0])[idx] = 0u;
    reinterpret_cast<uint32_t*>(&k3tab[0][0][0])[idx] = 0u;
  }
  for (int idx = tid; idx < 200; idx += NTHR)          // s1(-1) = 0
    k1f[0][120 + idx] = make_float4(0.f, 0.f, 0.f, 0.f);
  for (int idx = tid; idx < 12 * 200; idx += NTHR)
    w4_lds[idx / 200][idx % 200] = W4[idx];
  for (int idx = tid; idx < 3 * ROWS; idx += NTHR) bbL[idx] = bbG[idx];
  for (int idx = tid; idx < 3 * 200; idx += NTHR) saL[idx] = saG[idx];
  if (tid < 480) {                                     // x(0) -> k1f[0]
    const int bat = tid / 120, cf = tid - bat * 120;
    const int c = cf / 40, f = cf - c * 40;
    reinterpret_cast<float*>(&k1f[0][cf])[bat] =
        x[(((size_t)(bg * 4 + bat) * 3 + c) * T_STEPS) * 40 + f];
  }

  v2f d[5][2];
#pragma unroll
  for (int k = 0; k < 5; ++k) { d[k][0] = (v2f){0.f, 0.f}; d[k][1] = (v2f){0.f, 0.f}; }

  // readout constants (waves 11-13: 192 threads)
  float m4_reg = 0.0f, m4_acc = 0.0f, a4 = 0.0f, b4r = 0.0f;
  if (tid >= 704 && tid < 896) {
    const int o = (tid - 704) >> 4;
    a4 = sigmoidf(tm4[o]); b4r = b4[o];
  }
  __syncthreads();

  const int lane = tid & 63;

  for (int u = 0; u <= T_STEPS + 2; ++u) {
    const int cur = u & 1, oth = cur ^ 1;
    const uint8_t* k1b = reinterpret_cast<const uint8_t*>(&k1f[cur][0]);
    const uint8_t* k2b = reinterpret_cast<const uint8_t*>(&k2tab[oth][0][0]);
    const uint8_t* k3b = reinterpret_cast<const uint8_t*>(&k3tab[cur][0][0]);
    const bool runL1 = (u <= T_STEPS - 1);
    const bool runL2 = (u >= 1 && u <= T_STEPS);
    const bool runL3 = (u >= 2 && u <= T_STEPS + 1);
#pragma unroll
    for (int k = 0; k < 5; ++k) {
      const int id = wv + 16 * k;
      if (id >= 75) break;                   // wave-uniform
      const int layer = id / 25;
      const int r = (id - layer * 25) * 64 + lane;
      if (layer == 0) {
        if (runL1)
          slot_compute<NP1, true, true, false, true>(
              tid, r, ent1, k1b, bbL, saL, d[k], s_lds[0], mem_lds[0],
              k2tab[cur], k2tab[cur], k1f[oth]);
      } else if (layer == 1) {
        if (runL2)
          slot_compute<NP23, false, true, true, false>(
              tid, r, ent2, k2b, bbL + ROWS, saL + 200,
              d[k], s_lds[1], mem_lds[1], k3tab[oth], k2tab[cur] + 200, nullptr);
      } else {
        if (runL3)
          slot_compute<NP23, false, false, true, false>(
              tid, r, ent3, k3b, bbL + 2 * ROWS, saL + 400,
              d[k], s_lds[2], mem_lds[2], nullptr, k3tab[oth] + 200, nullptr);
      }
    }
    // ---- light-wave duties ---------------------------------------------
    if (wv >= 14) {
      // x-stage for t = u+1
      if (u + 1 <= T_STEPS - 1) {
        const int rid = tid - 896;
        for (int e = rid; e < 480; e += 128) {
          const int bat = e / 120, cf = e - bat * 120;
          const int c = cf / 40, f = cf - c * 40;
          reinterpret_cast<float*>(&k1f[oth][cf])[bat] =
              x[(((size_t)(bg * 4 + bat) * 3 + c) * T_STEPS + (u + 1)) * 40 + f];
        }
      }
    } else if (wv >= 11) {
      // readout for t_r = u-3 (s3(t_r) lives in k3tab[cur][200..])
      if (u >= 3) {
        const int rid = tid - 704;
        const int sub = rid & 3;
        float part = 0.0f;
#pragma unroll 10
        for (int m = 0; m < 50; ++m) {
          const int n = 4 * m + sub;
          part = fmaf(w4_lds[rid >> 4][n], (float)k3tab[cur][200 + n][(rid >> 2) & 3], part);
        }
        part += __shfl_xor(part, 1);
        part += __shfl_xor(part, 2);
        const float dot = b4r + part;
        m4_reg = a4 * m4_reg + (1.0f - a4) * dot;
        m4_acc += m4_reg;
      }
    }
    __syncthreads();
  }

  // ---- epilogue: log_softmax(acc / T) ----------------------------------
  if (tid >= 704 && tid < 896 && ((tid - 704) & 3) == 0) {
    const int rid = tid - 704;
    smx[rid >> 4][(rid >> 2) & 3] = m4_acc * (1.0f / (float)T_STEPS);
  }
  __syncthreads();
  if (tid < 4) {
    const int bat = tid;
    float v[12], mx = -1e30f;
#pragma unroll
    for (int o = 0; o < 12; ++o) { v[o] = smx[o][bat]; mx = fmaxf(mx, v[o]); }
    float s = 0.0f;
#pragma unroll
    for (int o = 0; o < 12; ++o) s += expf(v[o] - mx);
    const float ls = logf(s);
#pragma unroll
    for (int o = 0; o < 12; ++o)
      out[((size_t)(bg * 4 + bat)) * 12 + o] = v[o] - mx - ls;
  }
}

// ---------------------------------------------------------------------------
extern "C" void kernel_launch(void* const* d_in, const int* in_sizes, int n_in,
                              void* d_out, int out_size, void* d_ws, size_t ws_size,
                              hipStream_t stream) {
  (void)in_sizes; (void)n_in; (void)out_size; (void)ws_size;
  const float* x   = (const float*)d_in[0];
  const float* W1  = (const float*)d_in[1];
  const float* b1  = (const float*)d_in[2];
  const float* tm1 = (const float*)d_in[3];
  const float* tn1 = (const float*)d_in[4];
  const float* W2  = (const float*)d_in[5];
  const float* b2  = (const float*)d_in[6];
  const float* tm2 = (const float*)d_in[7];
  const float* tn2 = (const float*)d_in[8];
  const float* W3  = (const float*)d_in[9];
  const float* b3  = (const float*)d_in[10];
  const float* tm3 = (const float*)d_in[11];
  const float* tn3 = (const float*)d_in[12];
  const float* W4  = (const float*)d_in[13];
  const float* b4  = (const float*)d_in[14];
  const float* tm4 = (const float*)d_in[15];

  uint8_t* ws = (uint8_t*)d_ws;
  const float4* entB = (const float4*)(ws + ENT_OFF);
  const float4* ent1 = entB;
  const float4* ent2 = entB + PO2;
  const float4* ent3 = entB + PO3;
  const float2* bbG  = (const float2*)(ws + BB_OFF);
  const float*  saG  = (const float*)(ws + SA_OFF);

  prep_kernel<<<dim3(19), dim3(256), 0, stream>>>(
      W1, W2, W3, b1, tn1, tm1, b2, tn2, tm2, b3, tn3, tm3, ws);
  snn_main<<<dim3(NBLK), dim3(NTHR), 0, stream>>>(
      x, W4, b4, tm4, ent1, ent2, ent3, bbG, saG, (float*)d_out);
}

// Round 18
// 2646.323 us; speedup vs baseline: 4.0529x; 1.0255x over previous
//
#include <hip/hip_runtime.h>
#include <stdint.h>

#define T_STEPS 101
#define ROWS 1600
#define NTHR 1024
#define NBLK 256            /* 4 batches per block, 1024 batches total */
#define NP1 20              /* L1: 40 nz = 20 pairs (exactly 40 by mask construction) */
#define NP23 25             /* L2/3: 50 nz = 25 pairs (exactly 50) */
#define PO2 (NP1 * ROWS)               /* 32000 pairs */
#define PO3 (PO2 + NP23 * ROWS)        /* 72000 */
#define NPTOT (PO3 + NP23 * ROWS)      /* 112000 pairs */

/* ws byte offsets (r15 layout: 12 B/pair across two SoA streams) */
#define W2_OFF 0
#define C2_OFF (NPTOT * 8)                   /* 896000  */
#define BB_OFF (C2_OFF + NPTOT * 4)          /* 1344000 */
#define SA_OFF (BB_OFF + 3 * ROWS * 8)       /* 1382400 */

typedef float v2f __attribute__((ext_vector_type(2)));
__device__ __forceinline__ v2f fma2(v2f a, v2f b, v2f c) {
  return __builtin_elementwise_fma(a, b, c);   // v_pk_fma_f32: per-comp IEEE fma
}

__device__ __forceinline__ float sigmoidf(float v) { return 1.0f / (1.0f + expf(-v)); }

// ---------------------------------------------------------------------------
// Prep (r15-verified): paired CSR streams. w2[p][1600] float2 = weights
// (2j, 2j+1); c2[p][1600] u32 = two u16 byte-offsets. Ascending col order ==
// round-1's verified op order; padding w=0/c=0 exact. Offset scales:
// L1 col*16 (float4 k1 table), L2/3 col*4 (u8-quad tables).
// ---------------------------------------------------------------------------
__global__ void prep_kernel(const float* __restrict__ W1, const float* __restrict__ W2,
                            const float* __restrict__ W3,
                            const float* __restrict__ b1, const float* __restrict__ tn1,
                            const float* __restrict__ tm1,
                            const float* __restrict__ b2, const float* __restrict__ tn2,
                            const float* __restrict__ tm2,
                            const float* __restrict__ b3, const float* __restrict__ tn3,
                            const float* __restrict__ tm3,
                            uint8_t* __restrict__ ws) {
  int gid = blockIdx.x * blockDim.x + threadIdx.x;
  if (gid >= 3 * ROWS) return;
  int l = gid / ROWS, r = gid - l * ROWS;
  const float *W, *bb, *tn, *tm; int in_f, knz, np, poff, scale;
  if (l == 0)      { W = W1; bb = b1; tn = tn1; tm = tm1; in_f = 320; knz = 40; np = NP1;  poff = 0;   scale = 16; }
  else if (l == 1) { W = W2; bb = b2; tn = tn2; tm = tm2; in_f = 400; knz = 50; np = NP23; poff = PO2; scale = 4; }
  else             { W = W3; bb = b3; tn = tn3; tm = tm3; in_f = 400; knz = 50; np = NP23; poff = PO3; scale = 4; }
  float2* w2 = (float2*)(ws + W2_OFF) + poff;
  uint32_t* c2 = (uint32_t*)(ws + C2_OFF) + poff;
  float wl[52]; uint32_t cl[52];
  int cnt = 0;
  for (int col = 0; col < in_f; ++col) {
    float w = W[(size_t)r * in_f + col];
    if (w != 0.0f && cnt < knz) { wl[cnt] = w; cl[cnt] = (uint32_t)(col * scale); ++cnt; }
  }
  for (; cnt < 2 * np; ++cnt) { wl[cnt] = 0.0f; cl[cnt] = 0u; }
  for (int p = 0; p < np; ++p) {
    w2[p * ROWS + r] = make_float2(wl[2 * p], wl[2 * p + 1]);
    c2[p * ROWS + r] = cl[2 * p] | (cl[2 * p + 1] << 16);
  }
  ((float2*)(ws + BB_OFF))[l * ROWS + r] = make_float2(sigmoidf(tn[r]), bb[r]);
  if (r < 200) ((float*)(ws + SA_OFF))[l * 200 + r] = sigmoidf(tm[r]);
}

// ---------------------------------------------------------------------------
// One row-slot, 4 batch lanes. Per pair: float2 w-load + u32 col-load
// (12 B/pair, r15's coalesced streams) + 2 LDS reads + 4 v_pk_fma_f32
// (r16/r17-verified bitwise: pk_fma = 2x IEEE fma). Leader writes spike
// word into consumer tables per template flags.
// ---------------------------------------------------------------------------
template<int NP, bool F32, bool WA, bool WB, bool WK1>
__device__ __forceinline__ void slot_compute(
    int tid, int r,
    const float2* __restrict__ w2, const uint32_t* __restrict__ c2,
    const uint8_t* __restrict__ ktab,
    const float2* __restrict__ bbL, const float* __restrict__ saL,
    v2f (&dreg)[2], uint8_t (*s_l)[4], float (*mem_l)[4],
    uint8_t (*spA)[4], uint8_t (*spB)[4], float4* k1n)
{
  const float2 bb = bbL[r];
  const float bt = bb.x;
  v2f a01 = {bb.y, bb.y}, a23 = {bb.y, bb.y};
  const float2* wp = w2 + r;
  const uint32_t* cp = c2 + r;
#pragma unroll 5
  for (int p = 0; p < NP; ++p) {
    const float2 w = wp[(size_t)p * ROWS];
    const uint32_t c = cp[(size_t)p * ROWS];
    const v2f wx = {w.x, w.x}, wy = {w.y, w.y};
    if constexpr (F32) {
      { const float4 kv = *reinterpret_cast<const float4*>(ktab + (c & 0xffffu));
        a01 = fma2(wx, (v2f){kv.x, kv.y}, a01);
        a23 = fma2(wx, (v2f){kv.z, kv.w}, a23); }
      { const float4 kv = *reinterpret_cast<const float4*>(ktab + (c >> 16));
        a01 = fma2(wy, (v2f){kv.x, kv.y}, a01);
        a23 = fma2(wy, (v2f){kv.z, kv.w}, a23); }
    } else {
      { const uint32_t q = *reinterpret_cast<const uint32_t*>(ktab + (c & 0xffffu));
        a01 = fma2(wx, (v2f){(float)(q & 0xffu), (float)((q >> 8) & 0xffu)}, a01);
        a23 = fma2(wx, (v2f){(float)((q >> 16) & 0xffu), (float)(q >> 24)}, a23); }
      { const uint32_t q = *reinterpret_cast<const uint32_t*>(ktab + (c >> 16));
        a01 = fma2(wy, (v2f){(float)(q & 0xffu), (float)((q >> 8) & 0xffu)}, a01);
        a23 = fma2(wy, (v2f){(float)((q >> 16) & 0xffu), (float)(q >> 24)}, a23); }
    }
  }
  const v2f bt2 = {bt, bt}, ob2 = {1.0f - bt, 1.0f - bt};
  const v2f d01v = fma2(bt2, dreg[0], ob2 * a01);
  const v2f d23v = fma2(bt2, dreg[1], ob2 * a23);
  dreg[0] = d01v; dreg[1] = d23v;
  float d0 = d01v.x, d1 = d01v.y, d2 = d23v.x, d3 = d23v.y;
  d0 += __shfl_xor(d0, 1); d0 += __shfl_xor(d0, 2); d0 += __shfl_xor(d0, 4);
  d1 += __shfl_xor(d1, 1); d1 += __shfl_xor(d1, 2); d1 += __shfl_xor(d1, 4);
  d2 += __shfl_xor(d2, 1); d2 += __shfl_xor(d2, 2); d2 += __shfl_xor(d2, 4);
  d3 += __shfl_xor(d3, 1); d3 += __shfl_xor(d3, 2); d3 += __shfl_xor(d3, 4);
  if ((tid & 7) == 0) {
    const int n = r >> 3;
    const float al = saL[n], oa = 1.0f - al;
    float4 mv = *reinterpret_cast<float4*>(&mem_l[n][0]);
    const uint32_t so = *reinterpret_cast<uint32_t*>(&s_l[n][0]);
    const float m0 = fmaf(mv.x - (float)(so & 0xffu),         al, oa * d0);
    const float m1 = fmaf(mv.y - (float)((so >> 8) & 0xffu),  al, oa * d1);
    const float m2 = fmaf(mv.z - (float)((so >> 16) & 0xffu), al, oa * d2);
    const float m3 = fmaf(mv.w - (float)(so >> 24),           al, oa * d3);
    *reinterpret_cast<float4*>(&mem_l[n][0]) = make_float4(m0, m1, m2, m3);
    const uint32_t sn = (m0 > 1.0f ? 1u : 0u) | (m1 > 1.0f ? 0x100u : 0u)
                      | (m2 > 1.0f ? 0x10000u : 0u) | (m3 > 1.0f ? 0x1000000u : 0u);
    *reinterpret_cast<uint32_t*>(&s_l[n][0]) = sn;
    if constexpr (WA) *reinterpret_cast<uint32_t*>(&spA[n][0]) = sn;
    if constexpr (WB) *reinterpret_cast<uint32_t*>(&spB[n][0]) = sn;
    if constexpr (WK1)
      k1n[120 + n] = make_float4(m0 > 1.0f ? 1.0f : 0.0f, m1 > 1.0f ? 1.0f : 0.0f,
                                 m2 > 1.0f ? 1.0f : 0.0f, m3 > 1.0f ? 1.0f : 0.0f);
  }
}

// ---------------------------------------------------------------------------
// Main kernel: 256 blocks x 1024 threads, 4 batches/block, layer-skewed
// pipeline (verified r15 schedule): super-step u runs {L1(u), L2(u-1),
// L3(u-2), readout(u-3), x-stage(u+1)} in one barrier phase; 75 wave-slots
// grid-strided over 16 waves.
// ---------------------------------------------------------------------------
__global__ void __launch_bounds__(NTHR)
snn_main(const float* __restrict__ x,
         const float* __restrict__ W4, const float* __restrict__ b4,
         const float* __restrict__ tm4,
         const float2* __restrict__ w2G, const uint32_t* __restrict__ c2G,
         const float2* __restrict__ bbG, const float* __restrict__ saG,
         float* __restrict__ out)
{
  __shared__ __align__(16) float4   k1f[2][320];       // parity: x(t) | s1(t-1)
  __shared__ __align__(4)  uint8_t  k2tab[2][400][4];  // parity: s1(t) | s2(t-1)
  __shared__ __align__(4)  uint8_t  k3tab[2][400][4];  // parity: s2(t) | s3(t-1)
  __shared__ __align__(4)  uint8_t  s_lds[3][200][4];
  __shared__ __align__(16) float    mem_lds[3][200][4];
  __shared__ float  w4_lds[12][201];
  __shared__ float2 bbL[3 * ROWS];
  __shared__ float  saL[3 * 200];
  __shared__ float  smx[12][4];

  const int tid = threadIdx.x;
  const int wv  = tid >> 6;
  const int bg  = blockIdx.x;          // batches bg*4 .. bg*4+3

  for (int idx = tid; idx < 600; idx += NTHR) {
    reinterpret_cast<uint32_t*>(&s_lds[0][0][0])[idx] = 0u;
    reinterpret_cast<float4*>(&mem_lds[0][0][0])[idx] = make_float4(0.f, 0.f, 0.f, 0.f);
  }
  for (int idx = tid; idx < 800; idx += NTHR) {        // zero both parities
    reinterpret_cast<uint32_t*>(&k2tab[0][0][0])[idx] = 0u;
    reinterpret_cast<uint32_t*>(&k3tab[0][0][0])[idx] = 0u;
  }
  for (int idx = tid; idx < 200; idx += NTHR)          // s1(-1) = 0
    k1f[0][120 + idx] = make_float4(0.f, 0.f, 0.f, 0.f);
  for (int idx = tid; idx < 12 * 200; idx += NTHR)
    w4_lds[idx / 200][idx % 200] = W4[idx];
  for (int idx = tid; idx < 3 * ROWS; idx += NTHR) bbL[idx] = bbG[idx];
  for (int idx = tid; idx < 3 * 200; idx += NTHR) saL[idx] = saG[idx];
  if (tid < 480) {                                     // x(0) -> k1f[0]
    const int bat = tid / 120, cf = tid - bat * 120;
    const int c = cf / 40, f = cf - c * 40;
    reinterpret_cast<float*>(&k1f[0][cf])[bat] =
        x[(((size_t)(bg * 4 + bat) * 3 + c) * T_STEPS) * 40 + f];
  }

  v2f d[5][2];
#pragma unroll
  for (int k = 0; k < 5; ++k) { d[k][0] = (v2f){0.f, 0.f}; d[k][1] = (v2f){0.f, 0.f}; }

  // readout constants (waves 11-13: 192 threads)
  float m4_reg = 0.0f, m4_acc = 0.0f, a4 = 0.0f, b4r = 0.0f;
  if (tid >= 704 && tid < 896) {
    const int o = (tid - 704) >> 4;
    a4 = sigmoidf(tm4[o]); b4r = b4[o];
  }
  __syncthreads();

  const int lane = tid & 63;

  for (int u = 0; u <= T_STEPS + 2; ++u) {
    const int cur = u & 1, oth = cur ^ 1;
    const uint8_t* k1b = reinterpret_cast<const uint8_t*>(&k1f[cur][0]);
    const uint8_t* k2b = reinterpret_cast<const uint8_t*>(&k2tab[oth][0][0]);
    const uint8_t* k3b = reinterpret_cast<const uint8_t*>(&k3tab[cur][0][0]);
    const bool runL1 = (u <= T_STEPS - 1);
    const bool runL2 = (u >= 1 && u <= T_STEPS);
    const bool runL3 = (u >= 2 && u <= T_STEPS + 1);
#pragma unroll
    for (int k = 0; k < 5; ++k) {
      const int id = wv + 16 * k;
      if (id >= 75) break;                   // wave-uniform
      const int layer = id / 25;
      const int r = (id - layer * 25) * 64 + lane;
      if (layer == 0) {
        if (runL1)
          slot_compute<NP1, true, true, false, true>(
              tid, r, w2G, c2G, k1b, bbL, saL, d[k], s_lds[0], mem_lds[0],
              k2tab[cur], k2tab[cur], k1f[oth]);
      } else if (layer == 1) {
        if (runL2)
          slot_compute<NP23, false, true, true, false>(
              tid, r, w2G + PO2, c2G + PO2, k2b, bbL + ROWS, saL + 200,
              d[k], s_lds[1], mem_lds[1], k3tab[oth], k2tab[cur] + 200, nullptr);
      } else {
        if (runL3)
          slot_compute<NP23, false, false, true, false>(
              tid, r, w2G + PO3, c2G + PO3, k3b, bbL + 2 * ROWS, saL + 400,
              d[k], s_lds[2], mem_lds[2], nullptr, k3tab[oth] + 200, nullptr);
      }
    }
    // ---- light-wave duties ---------------------------------------------
    if (wv >= 14) {
      // x-stage for t = u+1
      if (u + 1 <= T_STEPS - 1) {
        const int rid = tid - 896;
        for (int e = rid; e < 480; e += 128) {
          const int bat = e / 120, cf = e - bat * 120;
          const int c = cf / 40, f = cf - c * 40;
          reinterpret_cast<float*>(&k1f[oth][cf])[bat] =
              x[(((size_t)(bg * 4 + bat) * 3 + c) * T_STEPS + (u + 1)) * 40 + f];
        }
      }
    } else if (wv >= 11) {
      // readout for t_r = u-3 (s3(t_r) lives in k3tab[cur][200..])
      if (u >= 3) {
        const int rid = tid - 704;
        const int sub = rid & 3;
        float part = 0.0f;
#pragma unroll 10
        for (int m = 0; m < 50; ++m) {
          const int n = 4 * m + sub;
          part = fmaf(w4_lds[rid >> 4][n], (float)k3tab[cur][200 + n][(rid >> 2) & 3], part);
        }
        part += __shfl_xor(part, 1);
        part += __shfl_xor(part, 2);
        const float dot = b4r + part;
        m4_reg = a4 * m4_reg + (1.0f - a4) * dot;
        m4_acc += m4_reg;
      }
    }
    __syncthreads();
  }

  // ---- epilogue: log_softmax(acc / T) ----------------------------------
  if (tid >= 704 && tid < 896 && ((tid - 704) & 3) == 0) {
    const int rid = tid - 704;
    smx[rid >> 4][(rid >> 2) & 3] = m4_acc * (1.0f / (float)T_STEPS);
  }
  __syncthreads();
  if (tid < 4) {
    const int bat = tid;
    float v[12], mx = -1e30f;
#pragma unroll
    for (int o = 0; o < 12; ++o) { v[o] = smx[o][bat]; mx = fmaxf(mx, v[o]); }
    float s = 0.0f;
#pragma unroll
    for (int o = 0; o < 12; ++o) s += expf(v[o] - mx);
    const float ls = logf(s);
#pragma unroll
    for (int o = 0; o < 12; ++o)
      out[((size_t)(bg * 4 + bat)) * 12 + o] = v[o] - mx - ls;
  }
}

// ---------------------------------------------------------------------------
extern "C" void kernel_launch(void* const* d_in, const int* in_sizes, int n_in,
                              void* d_out, int out_size, void* d_ws, size_t ws_size,
                              hipStream_t stream) {
  (void)in_sizes; (void)n_in; (void)out_size; (void)ws_size;
  const float* x   = (const float*)d_in[0];
  const float* W1  = (const float*)d_in[1];
  const float* b1  = (const float*)d_in[2];
  const float* tm1 = (const float*)d_in[3];
  const float* tn1 = (const float*)d_in[4];
  const float* W2  = (const float*)d_in[5];
  const float* b2  = (const float*)d_in[6];
  const float* tm2 = (const float*)d_in[7];
  const float* tn2 = (const float*)d_in[8];
  const float* W3  = (const float*)d_in[9];
  const float* b3  = (const float*)d_in[10];
  const float* tm3 = (const float*)d_in[11];
  const float* tn3 = (const float*)d_in[12];
  const float* W4  = (const float*)d_in[13];
  const float* b4  = (const float*)d_in[14];
  const float* tm4 = (const float*)d_in[15];

  uint8_t* ws = (uint8_t*)d_ws;
  const float2*   w2G = (const float2*)(ws + W2_OFF);
  const uint32_t* c2G = (const uint32_t*)(ws + C2_OFF);
  const float2*   bbG = (const float2*)(ws + BB_OFF);
  const float*    saG = (const float*)(ws + SA_OFF);

  prep_kernel<<<dim3(19), dim3(256), 0, stream>>>(
      W1, W2, W3, b1, tn1, tm1, b2, tn2, tm2, b3, tn3, tm3, ws);
  snn_main<<<dim3(NBLK), dim3(NTHR), 0, stream>>>(
      x, W4, b4, tm4, w2G, c2G, bbG, saG, (float*)d_out);
}